// Round 8
// baseline (3296.243 us; speedup 1.0000x reference)
//
#include <hip/hip_runtime.h>
#include <math.h>

// ===========================================================================
// ImplicitMap fExtractor, round 8: reverse-mode + 1-barrier 3-ring pipeline.
// Forward (11 layers): x as fp16 hi+lo pair (3-pass MFMA == fp32 z), store
//   [x_hi, x_lo] ping-pong + gate (fp16, per-layer buffer, pad cols = 0).
//   Layer-11 epilogue stores v10 = gate * W12[o] (backward seed) for free.
// Backward (10 GEMMs): v_{j-1} = (v_j @ W_j) * gate_{j-1}, single-pass fp16.
// Round-8 change (sync structure only, math identical to R7):
//   * 3-buffer LDS ring, stage-ahead-2, ONE s_barrier per K-step, NO
//     lgkmcnt(0) drain, no second barrier. Safety: stage(t+2) writes buf
//     (t-1)%3, which all waves finished reading before barrier(t) (their
//     ds_reads are consumed by MFMAs => returned before they arrive).
//   * fwd LDS 72KB (2 blocks/CU), bwd 36KB (4 blocks/CU).
// ===========================================================================

typedef unsigned short u16;
typedef _Float16 f16;
typedef f16   f16x8  __attribute__((ext_vector_type(8)));
typedef float f32x16 __attribute__((ext_vector_type(16)));

__device__ __forceinline__ u16   f2h(float x){ return __builtin_bit_cast(u16, (f16)x); }
__device__ __forceinline__ float h2f(u16 b){ return (float)__builtin_bit_cast(f16, b); }

__device__ __forceinline__ void glld16(const void* g, void* l){
  __builtin_amdgcn_global_load_lds(
      (const __attribute__((address_space(1))) unsigned*)g,
      (__attribute__((address_space(3))) unsigned*)l, 16, 0, 0);
}

template<int N> __device__ __forceinline__ void wait_vmcnt(){
  static_assert(N == 0 || N == 3 || N == 6, "unsupported vmcnt literal");
  if constexpr (N == 0) asm volatile("s_waitcnt vmcnt(0)" ::: "memory");
  if constexpr (N == 3) asm volatile("s_waitcnt vmcnt(3)" ::: "memory");
  if constexpr (N == 6) asm volatile("s_waitcnt vmcnt(6)" ::: "memory");
}

// m-band XCD swizzle: contiguous m-range per XCD, o-tile fastest inside.
__device__ __forceinline__ void xcd_map(int& bx, int& by){
  const int gx = gridDim.x, gy = gridDim.y;
  const int nwg = gx * gy;
  const int d   = by * gx + bx;
  if ((nwg & 7) == 0){
    const int q = nwg >> 3;
    const int t = (d & 7) * q + (d >> 3);
    by = t % gy;
    bx = t / gy;
  }
}

// ---------------------------------------------------------------------------
// Forward layer: z = [xh;xl] @ [Wh;Wl]^T (3-pass), gate+softplus epilogue.
// ---------------------------------------------------------------------------
template<bool LAST>
__global__ __launch_bounds__(256, 2)
void fwd_layer(const u16* __restrict__ Sin, long long psIn, int kpad,
               u16* __restrict__ SoutX, long long psOut,
               u16* __restrict__ Gout, int opitch,
               const u16* __restrict__ Wh, const u16* __restrict__ Wl,
               const float* __restrict__ bias, const float* __restrict__ w12,
               int cout)
{
  __shared__ u16 As[3][2][4][64][8];    // [ring][plane][kq][row][8]  24KB
  __shared__ u16 Bs[3][2][4][128][8];   // [ring][h][kq][row][8]      48KB

  int bx = blockIdx.x, by = blockIdx.y;
  xcd_map(bx, by);

  const int tid   = threadIdx.x;
  const int w     = tid >> 6;
  const int lane  = tid & 63;
  const int lrow  = lane & 31;
  const int lhalf = lane >> 5;
  const int mh    = w >> 1;
  const int oh    = w & 1;
  const int m0    = bx * 64;
  const int o0    = by * 128;

  f32x16 zinit = {};
  f32x16 accx[2];
  accx[0] = zinit; accx[1] = zinit;

  const u16* aSrc[2];
  #pragma unroll
  for (int p = 0; p < 2; ++p)
    aSrc[p] = Sin + (long long)p * psIn + (long long)(m0 + lane) * kpad + w * 8;
  const u16* bSrc[2][2];
  #pragma unroll
  for (int h = 0; h < 2; ++h){
    const u16* Wx = h ? Wl : Wh;
    #pragma unroll
    for (int hf = 0; hf < 2; ++hf)
      bSrc[h][hf] = Wx + (long long)(o0 + hf*64 + lane) * kpad + w * 8;
  }

  auto stage = [&](int buf, int kElem){
    #pragma unroll
    for (int p = 0; p < 2; ++p)
      glld16(aSrc[p] + kElem, &As[buf][p][w][0][0]);
    #pragma unroll
    for (int h = 0; h < 2; ++h)
      #pragma unroll
      for (int hf = 0; hf < 2; ++hf)
        glld16(bSrc[h][hf] + kElem, &Bs[buf][h][w][hf*64][0]);
  };

  auto compute = [&](int buf){
    __builtin_amdgcn_s_setprio(1);
    #pragma unroll
    for (int s = 0; s < 2; ++s){
      const int kq = s*2 + lhalf;
      f16x8 a0 = *(const f16x8*)&As[buf][0][kq][mh*32 + lrow][0];
      f16x8 a1 = *(const f16x8*)&As[buf][1][kq][mh*32 + lrow][0];
      #pragma unroll
      for (int f = 0; f < 2; ++f){
        const int oc = oh*64 + f*32 + lrow;
        f16x8 bh = *(const f16x8*)&Bs[buf][0][kq][oc][0];
        f16x8 bl = *(const f16x8*)&Bs[buf][1][kq][oc][0];
        accx[f] = __builtin_amdgcn_mfma_f32_32x32x16_f16(a0, bh, accx[f], 0,0,0);
        accx[f] = __builtin_amdgcn_mfma_f32_32x32x16_f16(a1, bh, accx[f], 0,0,0);
        accx[f] = __builtin_amdgcn_mfma_f32_32x32x16_f16(a0, bl, accx[f], 0,0,0);
      }
    }
    __builtin_amdgcn_s_setprio(0);
  };

  // ---- 3-ring, stage-ahead-2, ONE barrier per K-step ----
  const int nk = kpad >> 5;
  stage(0, 0);
  stage(1, 32);
  int bc = 0, bs = 2;
  for (int t = 0; t < nk; ++t){
    if (t + 1 < nk) wait_vmcnt<6>();   // buf t landed, keep t+1 in flight
    else            wait_vmcnt<0>();
    __builtin_amdgcn_s_barrier();      // all waves' buf-t loads landed; all
                                       // waves done reading buf (t-1) [ring]
    compute(bc);
    if (t + 2 < nk) stage(bs, (t + 2) * 32);
    bc = (bc == 2) ? 0 : bc + 1;
    bs = (bs == 2) ? 0 : bs + 1;
  }

  const int mb = m0 + mh*32;
  #pragma unroll
  for (int f = 0; f < 2; ++f){
    const int o = o0 + oh*64 + f*32 + lrow;
    if (o >= opitch) continue;
    const bool real = (o < cout);
    const float bo  = real ? bias[o] : 0.f;
    const float wf  = (LAST && real) ? w12[o] : 0.f;
    #pragma unroll
    for (int r = 0; r < 16; ++r){
      const int m = mb + (r & 3) + ((r >> 2) << 3) + (lhalf << 2);
      const float z    = accx[f][r] + bo;
      const float gate = 1.f / (1.f + expf(-100.f * z));
      const float sp   = fmaxf(z, 0.f) + 0.01f * log1pf(expf(-100.f * fabsf(z)));
      const long long idx = (long long)m * opitch + o;
      const u16 xh = f2h(sp);
      SoutX[idx]         = xh;
      SoutX[psOut + idx] = f2h(sp - h2f(xh));
      float gv;
      if (LAST) gv = gate * wf;                    // backward seed v10
      else      gv = real ? gate : 0.f;            // pad cols MUST be 0
      Gout[idx] = f2h(gv);
    }
  }
}

// ---------------------------------------------------------------------------
// Backward layer: u = v @ Wt (single fp16 pass); v' = u * gate_prev.
// ---------------------------------------------------------------------------
__global__ __launch_bounds__(256, 4)
void bwd_layer(const u16* __restrict__ Vin, int kpad,
               u16* __restrict__ Vout, int opitch,
               const u16* __restrict__ Gprev, const u16* __restrict__ Wt)
{
  __shared__ u16 As[3][4][64][8];    // 12KB
  __shared__ u16 Bs[3][4][128][8];   // 24KB

  int bx = blockIdx.x, by = blockIdx.y;
  xcd_map(bx, by);

  const int tid   = threadIdx.x;
  const int w     = tid >> 6;
  const int lane  = tid & 63;
  const int lrow  = lane & 31;
  const int lhalf = lane >> 5;
  const int mh    = w >> 1;
  const int oh    = w & 1;
  const int m0    = bx * 64;
  const int o0    = by * 128;

  f32x16 zinit = {};
  f32x16 acc[2];
  acc[0] = zinit; acc[1] = zinit;

  const u16* aSrc = Vin + (long long)(m0 + lane) * kpad + w * 8;
  const u16* bSrc[2];
  #pragma unroll
  for (int hf = 0; hf < 2; ++hf)
    bSrc[hf] = Wt + (long long)(o0 + hf*64 + lane) * kpad + w * 8;

  auto stage = [&](int buf, int kElem){
    glld16(aSrc + kElem, &As[buf][w][0][0]);
    #pragma unroll
    for (int hf = 0; hf < 2; ++hf)
      glld16(bSrc[hf] + kElem, &Bs[buf][w][hf*64][0]);
  };

  auto compute = [&](int buf){
    __builtin_amdgcn_s_setprio(1);
    #pragma unroll
    for (int s = 0; s < 2; ++s){
      const int kq = s*2 + lhalf;
      f16x8 a = *(const f16x8*)&As[buf][kq][mh*32 + lrow][0];
      #pragma unroll
      for (int f = 0; f < 2; ++f){
        const int oc = oh*64 + f*32 + lrow;
        f16x8 b = *(const f16x8*)&Bs[buf][kq][oc][0];
        acc[f] = __builtin_amdgcn_mfma_f32_32x32x16_f16(a, b, acc[f], 0,0,0);
      }
    }
    __builtin_amdgcn_s_setprio(0);
  };

  const int nk = kpad >> 5;
  stage(0, 0);
  stage(1, 32);
  int bc = 0, bs = 2;
  for (int t = 0; t < nk; ++t){
    if (t + 1 < nk) wait_vmcnt<3>();
    else            wait_vmcnt<0>();
    __builtin_amdgcn_s_barrier();
    compute(bc);
    if (t + 2 < nk) stage(bs, (t + 2) * 32);
    bc = (bc == 2) ? 0 : bc + 1;
    bs = (bs == 2) ? 0 : bs + 1;
  }

  const int mb = m0 + mh*32;
  #pragma unroll
  for (int f = 0; f < 2; ++f){
    const int o = o0 + oh*64 + f*32 + lrow;
    if (o >= opitch) continue;
    #pragma unroll
    for (int r = 0; r < 16; ++r){
      const int m = mb + (r & 3) + ((r >> 2) << 3) + (lhalf << 2);
      const long long idx = (long long)m * opitch + o;
      Vout[idx] = f2h(acc[f][r] * h2f(Gprev[idx]));   // gate pads are 0
    }
  }
}

// z output: out1[m] = (xh+xl)[m,:] . W12 + b12.
__global__ __launch_bounds__(256)
void final_z(const u16* __restrict__ Sx, long long ps, int kpad,
             const float* __restrict__ W12, const float* __restrict__ b12,
             float* __restrict__ out1, int cin, int mBase)
{
  const int lane = threadIdx.x & 63;
  const int wv   = threadIdx.x >> 6;
  const int m = blockIdx.x * 4 + wv;
  const u16* row = Sx + (long long)m * kpad;
  float s = 0.f;
  for (int c = lane; c < cin; c += 64)
    s += (h2f(row[c]) + h2f(row[ps + c])) * W12[c];
  #pragma unroll
  for (int off = 32; off > 0; off >>= 1) s += __shfl_xor(s, off);
  if (lane == 0) out1[mBase + m] = s + b12[0];
}

// g output: out2[m, j] = sum_o v0[m,o] * W1[o, j], j=0..2.
__global__ __launch_bounds__(256)
void final_g(const u16* __restrict__ V0, int kpad,
             const float* __restrict__ W1, int cinW,
             float* __restrict__ out2, int width, int mBase)
{
  const int lane = threadIdx.x & 63;
  const int wv   = threadIdx.x >> 6;
  const int m = blockIdx.x * 4 + wv;
  const u16* row = V0 + (long long)m * kpad;
  float g0 = 0.f, g1 = 0.f, g2 = 0.f;
  for (int o = lane; o < width; o += 64){
    const float v = h2f(row[o]);
    const float* wr = W1 + (long long)o * cinW;
    g0 += v * wr[0]; g1 += v * wr[1]; g2 += v * wr[2];
  }
  #pragma unroll
  for (int off = 32; off > 0; off >>= 1){
    g0 += __shfl_xor(g0, off); g1 += __shfl_xor(g1, off); g2 += __shfl_xor(g2, off);
  }
  if (lane == 0){
    float* g = out2 + (long long)(mBase + m) * 3;
    g[0] = g0; g[1] = g1; g[2] = g2;
  }
}

// out3 = input_con (fp32) + padded fp16 hi/lo x0 for layer-1 GEMM.
__global__ void prep_input(const float* __restrict__ input,
                           const float* __restrict__ latent,
                           float* __restrict__ out3,
                           u16* __restrict__ x0, long long psX0, int N)
{
  const int m = blockIdx.x;
  const int b = m / N;
  const int c = threadIdx.x;
  if (c >= 288) return;
  float v = 0.f;
  if (c < 3) v = input[(long long)m*3 + c];
  else if (c < 259) v = latent[(long long)b*256 + (c - 3)];
  if (c < 259) out3[(long long)m*259 + c] = v;
  const u16 h = f2h(v);
  x0[(long long)m*288 + c]        = h;
  x0[psX0 + (long long)m*288 + c] = f2h(v - h2f(h));
}

// fp32 W -> zero-padded fp16 hi/lo (forward layout: row o, col c).
__global__ void split_w(const float* __restrict__ W, u16* __restrict__ wh,
                        u16* __restrict__ wl, int cout, int cin, int kpad, int total)
{
  const int idx = blockIdx.x * 256 + threadIdx.x;
  if (idx >= total) return;
  const int o = idx / kpad, c = idx % kpad;
  const float v = (o < cout && c < cin) ? W[(long long)o*cin + c] : 0.f;
  const u16 h = f2h(v);
  wh[idx] = h;
  wl[idx] = f2h(v - h2f(h));
}

// fp32 W (cout x cin) -> zero-padded transposed fp16: Wt[c, k] = W[k, c].
__global__ void split_wt(const float* __restrict__ W, u16* __restrict__ wt,
                         int cout, int cin, int kpad, int total)
{
  const int idx = blockIdx.x * 256 + threadIdx.x;
  if (idx >= total) return;
  const int c = idx / kpad, k = idx % kpad;
  const float v = (c < cin && k < cout) ? W[(long long)k*cin + c] : 0.f;
  wt[idx] = f2h(v);
}

extern "C" void kernel_launch(void* const* d_in, const int* in_sizes, int n_in,
                              void* d_out, int out_size, void* d_ws, size_t ws_size,
                              hipStream_t stream)
{
  static const int CIN [12] = {259,515,512,512,576,576,768,768,768,960,960,896};
  static const int COUT[12] = {515,512,512,576,576,768,768,768,960,960,896,1};
  int PF[11], KPF[11], NYF[11], NYB[11];
  for (int j = 0; j < 11; ++j){
    PF[j]  = (COUT[j] + 31) & ~31;             // state/gate pitch after layer j
    KPF[j] = (j == 0) ? 288 : PF[j-1];         // forward contraction pad
    NYF[j] = (COUT[j] + 127) / 128;            // forward o-tiles
    NYB[j] = (CIN[j] + 127) / 128;             // backward o-tiles (j>=1)
  }

  const float* input  = (const float*)d_in[0];
  const float* latent = (const float*)d_in[1];
  auto Wp = [&](int j){ return (const float*)d_in[2 + 2*j]; };
  auto Bp = [&](int j){ return (const float*)d_in[3 + 2*j]; };

  const int Bn = in_sizes[1] / 256;
  const int Nn = in_sizes[0] / (3 * Bn);
  const int M  = Bn * Nn;                       // 16384

  float* out1 = (float*)d_out;                  // (B,1,N)
  float* out2 = out1 + M;                       // (B,N,1,3)
  float* out3 = out2 + (size_t)M * 3;           // input_con (B,N,259) fp32

  // ---- ws carve-up: weights, x0 fixed; gates+bufs scale with Pc ----
  char* wsp = (char*)d_ws;
  u16 *WH[11], *WL[11], *WT[11];
  for (int j = 0; j < 11; ++j){
    const size_t sz = (size_t)NYF[j] * 128 * KPF[j] * 2;
    WH[j] = (u16*)wsp; wsp += sz;
    WL[j] = (u16*)wsp; wsp += sz;
  }
  for (int j = 1; j < 11; ++j){
    const size_t sz = (size_t)NYB[j] * 128 * PF[j] * 2;
    WT[j] = (u16*)wsp; wsp += sz;
  }
  u16* x0 = (u16*)wsp;
  const long long psX0 = (long long)M * 288;
  wsp += (size_t)2 * psX0 * 2;

  size_t sumPF = 0;
  for (int j = 0; j < 11; ++j) sumPF += (size_t)PF[j];
  const size_t used   = (size_t)(wsp - (char*)d_ws);
  const size_t remain = (ws_size > used) ? (ws_size - used) : 0;
  const size_t perPoint = sumPF * 2 + (size_t)2 * 2 * 960 * 2;  // gates + 2 xbufs
  long long pc = (long long)(remain / perPoint);
  pc &= ~63LL;
  int Pc = (int)((pc < (long long)M) ? pc : (long long)M);
  if (Pc < 64) Pc = 64;

  u16* gates[11];
  for (int j = 0; j < 11; ++j){
    gates[j] = (u16*)wsp; wsp += (size_t)Pc * PF[j] * 2;
  }
  u16* bufA = (u16*)wsp;                         // 2 planes x Pc x 960
  u16* bufB = bufA + (size_t)2 * Pc * 960;       // 2 planes (v ping-pong reuses)
  u16* vA = bufB;
  u16* vB = bufB + (size_t)Pc * 960;

  // ---- prologue ----
  prep_input<<<M, 320, 0, stream>>>(input, latent, out3, x0, psX0, Nn);
  for (int j = 0; j < 11; ++j){
    const int total = NYF[j] * 128 * KPF[j];
    split_w<<<(total + 255)/256, 256, 0, stream>>>(
        Wp(j), WH[j], WL[j], COUT[j], CIN[j], KPF[j], total);
  }
  for (int j = 1; j < 11; ++j){
    const int total = NYB[j] * 128 * PF[j];
    split_wt<<<(total + 255)/256, 256, 0, stream>>>(
        Wp(j), WT[j], COUT[j], CIN[j], PF[j], total);
  }

  // ---- chunked layer chain ----
  for (int cm0 = 0; cm0 < M; cm0 += Pc){
    const int Mc = (M - cm0 < Pc) ? (M - cm0) : Pc;
    const int gx = Mc / 64;

    // forward j=0..10; state alternates bufA/bufB
    u16* src = x0 + (long long)cm0 * 288;
    long long psSrc = psX0;
    int kp = 288;
    u16* dstTbl[2] = { bufA, bufB };
    for (int j = 0; j < 11; ++j){
      u16* dst = dstTbl[j & 1];
      dim3 g(gx, NYF[j]);
      if (j == 10)
        fwd_layer<true><<<g, 256, 0, stream>>>(
            src, psSrc, kp, dst, (long long)Pc * PF[j], gates[j], PF[j],
            WH[j], WL[j], Bp(j), Wp(11), COUT[j]);
      else
        fwd_layer<false><<<g, 256, 0, stream>>>(
            src, psSrc, kp, dst, (long long)Pc * PF[j], gates[j], PF[j],
            WH[j], WL[j], Bp(j), nullptr, COUT[j]);
      src = dst; psSrc = (long long)Pc * PF[j]; kp = PF[j];
    }

    // z output from x_11
    final_z<<<Mc/4, 256, 0, stream>>>(
        src, psSrc, kp, Wp(11), Bp(11), out1, CIN[11], cm0);

    // backward j=10..1: v_j -> v_{j-1}; v_10 seed lives in gates[10]
    u16* vin = gates[10];
    for (int j = 10; j >= 1; --j){
      u16* vout = (j & 1) ? vB : vA;
      dim3 g(gx, NYB[j]);
      bwd_layer<<<g, 256, 0, stream>>>(
          vin, PF[j], vout, PF[j-1], gates[j-1], WT[j]);
      vin = vout;
    }

    // g output from v_0
    final_g<<<Mc/4, 256, 0, stream>>>(
        vin, PF[0], Wp(0), CIN[0], out2, COUT[0], cm0);
  }
}

// Round 9
// 2531.180 us; speedup vs baseline: 1.3023x; 1.3023x over previous
//
#include <hip/hip_runtime.h>
#include <math.h>

// ===========================================================================
// ImplicitMap fExtractor, round 9: reverse-mode, occupancy-first geometry.
// Forward: x fp16 hi+lo pair (3-pass MFMA == fp32 z); gates stored per layer;
//   layer-11 epilogue emits backward seed v10 = gate*W12.
// Backward: v_{j-1} = (v_j @ W_j^T-pre) * gate_{j-1}, single fp16 pass.
// Round-9 change (geometry only; 2-buf/2-barrier pipeline and math = R7):
//   * fwd: BM=128 BN=64, 8 waves/block, LDS 48KB -> 3 blk/CU, 24 waves/CU
//     (2x R7's wave count; per-iter critical path halves: 6 MFMA, 8 ds_read)
//   * bwd: BM=128 BN=128, 8 waves, LDS 32KB -> 4 blk/CU = 32 waves/CU (full),
//     grid halves -> half the sequential block-iterations
// ===========================================================================

typedef unsigned short u16;
typedef _Float16 f16;
typedef f16   f16x8  __attribute__((ext_vector_type(8)));
typedef float f32x16 __attribute__((ext_vector_type(16)));

__device__ __forceinline__ u16   f2h(float x){ return __builtin_bit_cast(u16, (f16)x); }
__device__ __forceinline__ float h2f(u16 b){ return (float)__builtin_bit_cast(f16, b); }

__device__ __forceinline__ void glld16(const void* g, void* l){
  __builtin_amdgcn_global_load_lds(
      (const __attribute__((address_space(1))) unsigned*)g,
      (__attribute__((address_space(3))) unsigned*)l, 16, 0, 0);
}

template<int N> __device__ __forceinline__ void wait_vmcnt(){
  static_assert(N == 0 || N == 2 || N == 3, "unsupported vmcnt literal");
  if constexpr (N == 0) asm volatile("s_waitcnt vmcnt(0)" ::: "memory");
  if constexpr (N == 2) asm volatile("s_waitcnt vmcnt(2)" ::: "memory");
  if constexpr (N == 3) asm volatile("s_waitcnt vmcnt(3)" ::: "memory");
}

// m-band XCD swizzle: contiguous m-range per XCD, o-tile fastest inside.
__device__ __forceinline__ void xcd_map(int& bx, int& by){
  const int gx = gridDim.x, gy = gridDim.y;
  const int nwg = gx * gy;
  const int d   = by * gx + bx;
  if ((nwg & 7) == 0){
    const int q = nwg >> 3;
    const int t = (d & 7) * q + (d >> 3);
    by = t % gy;
    bx = t / gy;
  }
}

// ---------------------------------------------------------------------------
// Forward layer: 128m x 64o block, 8 waves, wave tile 32x32, 3-pass split.
// ---------------------------------------------------------------------------
template<bool LAST>
__global__ __launch_bounds__(512, 6)
void fwd_layer(const u16* __restrict__ Sin, long long psIn, int kpad,
               u16* __restrict__ SoutX, long long psOut,
               u16* __restrict__ Gout, int opitch,
               const u16* __restrict__ Wh, const u16* __restrict__ Wl,
               const float* __restrict__ bias, const float* __restrict__ w12,
               int cout)
{
  __shared__ u16 As[2][2][4][128][8];   // [buf][plane][kq][row][8]  32KB
  __shared__ u16 Bs[2][2][4][64][8];    // [buf][h][kq][row][8]      16KB

  int bx = blockIdx.x, by = blockIdx.y;
  xcd_map(bx, by);

  const int tid   = threadIdx.x;
  const int w     = __builtin_amdgcn_readfirstlane(tid >> 6);  // 0..7
  const int lane  = tid & 63;
  const int lrow  = lane & 31;
  const int lhalf = lane >> 5;
  const int mh    = w >> 1;       // m-quarter (32 rows)
  const int on    = w & 1;        // o-half (32 cols)
  const int m0    = bx * 128;
  const int o0    = by * 64;

  f32x16 accx = {};

  // ---- per-wave staging chunks: 24 total (16 A + 8 B), 3 per wave ----
  const u16* gp[3];
  u16* lp[3];          // LDS dest in buffer 0 (wave-uniform)
  int  bstr[3];        // element stride buffer0 -> buffer1
  #pragma unroll
  for (int j = 0; j < 3; ++j){
    const int c = 3 * w + j;
    if (c < 16){
      const int pl = c >> 3, rem = c & 7, kq = rem >> 1, rs = rem & 1;
      gp[j]   = Sin + (long long)pl * psIn + (long long)(m0 + rs*64 + lane) * kpad + kq * 8;
      lp[j]   = &As[0][pl][kq][rs*64][0];
      bstr[j] = 2*4*128*8;
    } else {
      const int b = c - 16, h = b >> 2, kq = b & 3;
      gp[j]   = (h ? Wl : Wh) + (long long)(o0 + lane) * kpad + kq * 8;
      lp[j]   = &Bs[0][h][kq][0][0];
      bstr[j] = 2*4*64*8;
    }
  }

  auto stage = [&](int buf, int kElem){
    #pragma unroll
    for (int j = 0; j < 3; ++j)
      glld16(gp[j] + kElem, lp[j] + buf * bstr[j]);
  };

  auto compute = [&](int buf){
    __builtin_amdgcn_s_setprio(1);
    #pragma unroll
    for (int s = 0; s < 2; ++s){
      const int kq = s*2 + lhalf;
      f16x8 a0 = *(const f16x8*)&As[buf][0][kq][mh*32 + lrow][0];
      f16x8 a1 = *(const f16x8*)&As[buf][1][kq][mh*32 + lrow][0];
      f16x8 bh = *(const f16x8*)&Bs[buf][0][kq][on*32 + lrow][0];
      f16x8 bl = *(const f16x8*)&Bs[buf][1][kq][on*32 + lrow][0];
      accx = __builtin_amdgcn_mfma_f32_32x32x16_f16(a0, bh, accx, 0,0,0);
      accx = __builtin_amdgcn_mfma_f32_32x32x16_f16(a1, bh, accx, 0,0,0);
      accx = __builtin_amdgcn_mfma_f32_32x32x16_f16(a0, bl, accx, 0,0,0);
    }
    __builtin_amdgcn_s_setprio(0);
  };

  const int nk = kpad >> 5;
  stage(0, 0);
  stage(1, 32);
  int cur = 0;
  for (int t = 0; t < nk - 1; ++t){
    wait_vmcnt<3>();
    __builtin_amdgcn_s_barrier();
    compute(cur);
    asm volatile("s_waitcnt lgkmcnt(0)" ::: "memory");
    __builtin_amdgcn_s_barrier();
    if (t + 2 < nk) stage(cur, (t + 2) * 32);
    cur ^= 1;
  }
  wait_vmcnt<0>();
  __builtin_amdgcn_s_barrier();
  compute(cur);

  // ---- epilogue: D col=lane&31, row=(r&3)+8*(r>>2)+4*(lane>>5) ----
  const int o = o0 + on*32 + lrow;
  if (o >= opitch) return;
  const bool real = (o < cout);
  const float bo  = real ? bias[o] : 0.f;
  const float wf  = (LAST && real) ? w12[o] : 0.f;
  const int mb = m0 + mh*32;
  #pragma unroll
  for (int r = 0; r < 16; ++r){
    const int m = mb + (r & 3) + ((r >> 2) << 3) + (lhalf << 2);
    const float z    = accx[r] + bo;
    const float gate = 1.f / (1.f + expf(-100.f * z));
    const float sp   = fmaxf(z, 0.f) + 0.01f * log1pf(expf(-100.f * fabsf(z)));
    const long long idx = (long long)m * opitch + o;
    const u16 xh = f2h(sp);
    SoutX[idx]         = xh;
    SoutX[psOut + idx] = f2h(sp - h2f(xh));
    float gv;
    if (LAST) gv = gate * wf;                 // backward seed v10
    else      gv = real ? gate : 0.f;         // pad cols MUST be 0
    Gout[idx] = f2h(gv);
  }
}

// ---------------------------------------------------------------------------
// Backward layer: 128m x 128o block, 8 waves, wave tile 32x64, 1 fp16 pass.
// ---------------------------------------------------------------------------
__global__ __launch_bounds__(512, 8)
void bwd_layer(const u16* __restrict__ Vin, int kpad,
               u16* __restrict__ Vout, int opitch,
               const u16* __restrict__ Gprev, const u16* __restrict__ Wt)
{
  __shared__ u16 As[2][4][128][8];   // 16KB
  __shared__ u16 Bs[2][4][128][8];   // 16KB

  int bx = blockIdx.x, by = blockIdx.y;
  xcd_map(bx, by);

  const int tid   = threadIdx.x;
  const int w     = __builtin_amdgcn_readfirstlane(tid >> 6);
  const int lane  = tid & 63;
  const int lrow  = lane & 31;
  const int lhalf = lane >> 5;
  const int mh    = w >> 1;       // m-quarter (32 rows)
  const int on    = w & 1;        // o-half (64 cols)
  const int m0    = bx * 128;
  const int o0    = by * 128;

  f32x16 acc[2];
  acc[0] = f32x16{}; acc[1] = f32x16{};

  // ---- 16 chunks (8 A + 8 B), 2 per wave ----
  const u16* gp[2];
  u16* lp[2];
  #pragma unroll
  for (int j = 0; j < 2; ++j){
    const int c = 2 * w + j;
    if (c < 8){
      const int kq = c >> 1, rs = c & 1;
      gp[j] = Vin + (long long)(m0 + rs*64 + lane) * kpad + kq * 8;
      lp[j] = &As[0][kq][rs*64][0];
    } else {
      const int b = c - 8, kq = b >> 1, rs = b & 1;
      gp[j] = Wt + (long long)(o0 + rs*64 + lane) * kpad + kq * 8;
      lp[j] = &Bs[0][kq][rs*64][0];
    }
  }
  const int bstr = 4*128*8;   // same for As and Bs

  auto stage = [&](int buf, int kElem){
    #pragma unroll
    for (int j = 0; j < 2; ++j)
      glld16(gp[j] + kElem, lp[j] + buf * bstr);
  };

  auto compute = [&](int buf){
    __builtin_amdgcn_s_setprio(1);
    #pragma unroll
    for (int s = 0; s < 2; ++s){
      const int kq = s*2 + lhalf;
      f16x8 a = *(const f16x8*)&As[buf][kq][mh*32 + lrow][0];
      #pragma unroll
      for (int f = 0; f < 2; ++f){
        f16x8 b = *(const f16x8*)&Bs[buf][kq][on*64 + f*32 + lrow][0];
        acc[f] = __builtin_amdgcn_mfma_f32_32x32x16_f16(a, b, acc[f], 0,0,0);
      }
    }
    __builtin_amdgcn_s_setprio(0);
  };

  const int nk = kpad >> 5;
  stage(0, 0);
  stage(1, 32);
  int cur = 0;
  for (int t = 0; t < nk - 1; ++t){
    wait_vmcnt<2>();
    __builtin_amdgcn_s_barrier();
    compute(cur);
    asm volatile("s_waitcnt lgkmcnt(0)" ::: "memory");
    __builtin_amdgcn_s_barrier();
    if (t + 2 < nk) stage(cur, (t + 2) * 32);
    cur ^= 1;
  }
  wait_vmcnt<0>();
  __builtin_amdgcn_s_barrier();
  compute(cur);

  const int mb = m0 + mh*32;
  #pragma unroll
  for (int f = 0; f < 2; ++f){
    const int o = o0 + on*64 + f*32 + lrow;
    if (o >= opitch) continue;
    #pragma unroll
    for (int r = 0; r < 16; ++r){
      const int m = mb + (r & 3) + ((r >> 2) << 3) + (lhalf << 2);
      const long long idx = (long long)m * opitch + o;
      Vout[idx] = f2h(acc[f][r] * h2f(Gprev[idx]));   // gate pads are 0
    }
  }
}

// z output: out1[m] = (xh+xl)[m,:] . W12 + b12.
__global__ __launch_bounds__(256)
void final_z(const u16* __restrict__ Sx, long long ps, int kpad,
             const float* __restrict__ W12, const float* __restrict__ b12,
             float* __restrict__ out1, int cin, int mBase)
{
  const int lane = threadIdx.x & 63;
  const int wv   = threadIdx.x >> 6;
  const int m = blockIdx.x * 4 + wv;
  const u16* row = Sx + (long long)m * kpad;
  float s = 0.f;
  for (int c = lane; c < cin; c += 64)
    s += (h2f(row[c]) + h2f(row[ps + c])) * W12[c];
  #pragma unroll
  for (int off = 32; off > 0; off >>= 1) s += __shfl_xor(s, off);
  if (lane == 0) out1[mBase + m] = s + b12[0];
}

// g output: out2[m, j] = sum_o v0[m,o] * W1[o, j], j=0..2.
__global__ __launch_bounds__(256)
void final_g(const u16* __restrict__ V0, int kpad,
             const float* __restrict__ W1, int cinW,
             float* __restrict__ out2, int width, int mBase)
{
  const int lane = threadIdx.x & 63;
  const int wv   = threadIdx.x >> 6;
  const int m = blockIdx.x * 4 + wv;
  const u16* row = V0 + (long long)m * kpad;
  float g0 = 0.f, g1 = 0.f, g2 = 0.f;
  for (int o = lane; o < width; o += 64){
    const float v = h2f(row[o]);
    const float* wr = W1 + (long long)o * cinW;
    g0 += v * wr[0]; g1 += v * wr[1]; g2 += v * wr[2];
  }
  #pragma unroll
  for (int off = 32; off > 0; off >>= 1){
    g0 += __shfl_xor(g0, off); g1 += __shfl_xor(g1, off); g2 += __shfl_xor(g2, off);
  }
  if (lane == 0){
    float* g = out2 + (long long)(mBase + m) * 3;
    g[0] = g0; g[1] = g1; g[2] = g2;
  }
}

// out3 = input_con (fp32) + padded fp16 hi/lo x0 for layer-1 GEMM.
__global__ void prep_input(const float* __restrict__ input,
                           const float* __restrict__ latent,
                           float* __restrict__ out3,
                           u16* __restrict__ x0, long long psX0, int N)
{
  const int m = blockIdx.x;
  const int b = m / N;
  const int c = threadIdx.x;
  if (c >= 288) return;
  float v = 0.f;
  if (c < 3) v = input[(long long)m*3 + c];
  else if (c < 259) v = latent[(long long)b*256 + (c - 3)];
  if (c < 259) out3[(long long)m*259 + c] = v;
  const u16 h = f2h(v);
  x0[(long long)m*288 + c]        = h;
  x0[psX0 + (long long)m*288 + c] = f2h(v - h2f(h));
}

// fp32 W -> zero-padded fp16 hi/lo (forward layout: row o, col c).
__global__ void split_w(const float* __restrict__ W, u16* __restrict__ wh,
                        u16* __restrict__ wl, int cout, int cin, int kpad, int total)
{
  const int idx = blockIdx.x * 256 + threadIdx.x;
  if (idx >= total) return;
  const int o = idx / kpad, c = idx % kpad;
  const float v = (o < cout && c < cin) ? W[(long long)o*cin + c] : 0.f;
  const u16 h = f2h(v);
  wh[idx] = h;
  wl[idx] = f2h(v - h2f(h));
}

// fp32 W (cout x cin) -> zero-padded transposed fp16: Wt[c, k] = W[k, c].
__global__ void split_wt(const float* __restrict__ W, u16* __restrict__ wt,
                         int cout, int cin, int kpad, int total)
{
  const int idx = blockIdx.x * 256 + threadIdx.x;
  if (idx >= total) return;
  const int c = idx / kpad, k = idx % kpad;
  const float v = (c < cin && k < cout) ? W[(long long)k*cin + c] : 0.f;
  wt[idx] = f2h(v);
}

extern "C" void kernel_launch(void* const* d_in, const int* in_sizes, int n_in,
                              void* d_out, int out_size, void* d_ws, size_t ws_size,
                              hipStream_t stream)
{
  static const int CIN [12] = {259,515,512,512,576,576,768,768,768,960,960,896};
  static const int COUT[12] = {515,512,512,576,576,768,768,768,960,960,896,1};
  int PF[11], KPF[11], NYF[11], NYB[11];
  for (int j = 0; j < 11; ++j){
    PF[j]  = (COUT[j] + 31) & ~31;             // state/gate pitch after layer j
    KPF[j] = (j == 0) ? 288 : PF[j-1];         // forward contraction pad
    NYF[j] = (COUT[j] + 63) / 64;              // forward o-tiles (BN=64)
    NYB[j] = (CIN[j] + 127) / 128;             // backward o-tiles (BN=128)
  }

  const float* input  = (const float*)d_in[0];
  const float* latent = (const float*)d_in[1];
  auto Wp = [&](int j){ return (const float*)d_in[2 + 2*j]; };
  auto Bp = [&](int j){ return (const float*)d_in[3 + 2*j]; };

  const int Bn = in_sizes[1] / 256;
  const int Nn = in_sizes[0] / (3 * Bn);
  const int M  = Bn * Nn;                       // 16384

  float* out1 = (float*)d_out;                  // (B,1,N)
  float* out2 = out1 + M;                       // (B,N,1,3)
  float* out3 = out2 + (size_t)M * 3;           // input_con (B,N,259) fp32

  // ---- ws carve-up ----
  char* wsp = (char*)d_ws;
  u16 *WH[11], *WL[11], *WT[11];
  for (int j = 0; j < 11; ++j){
    const size_t sz = (size_t)NYF[j] * 64 * KPF[j] * 2;
    WH[j] = (u16*)wsp; wsp += sz;
    WL[j] = (u16*)wsp; wsp += sz;
  }
  for (int j = 1; j < 11; ++j){
    const size_t sz = (size_t)NYB[j] * 128 * PF[j] * 2;
    WT[j] = (u16*)wsp; wsp += sz;
  }
  u16* x0 = (u16*)wsp;
  const long long psX0 = (long long)M * 288;
  wsp += (size_t)2 * psX0 * 2;

  size_t sumPF = 0;
  for (int j = 0; j < 11; ++j) sumPF += (size_t)PF[j];
  const size_t used   = (size_t)(wsp - (char*)d_ws);
  const size_t remain = (ws_size > used) ? (ws_size - used) : 0;
  const size_t perPoint = sumPF * 2 + (size_t)2 * 2 * 960 * 2;  // gates + 2 xbufs
  long long pc = (long long)(remain / perPoint);
  pc &= ~127LL;
  int Pc = (int)((pc < (long long)M) ? pc : (long long)M);
  if (Pc < 128) Pc = 128;

  u16* gates[11];
  for (int j = 0; j < 11; ++j){
    gates[j] = (u16*)wsp; wsp += (size_t)Pc * PF[j] * 2;
  }
  u16* bufA = (u16*)wsp;                         // 2 planes x Pc x 960
  u16* bufB = bufA + (size_t)2 * Pc * 960;
  u16* vA = bufB;
  u16* vB = bufB + (size_t)Pc * 960;

  // ---- prologue ----
  prep_input<<<M, 320, 0, stream>>>(input, latent, out3, x0, psX0, Nn);
  for (int j = 0; j < 11; ++j){
    const int total = NYF[j] * 64 * KPF[j];
    split_w<<<(total + 255)/256, 256, 0, stream>>>(
        Wp(j), WH[j], WL[j], COUT[j], CIN[j], KPF[j], total);
  }
  for (int j = 1; j < 11; ++j){
    const int total = NYB[j] * 128 * PF[j];
    split_wt<<<(total + 255)/256, 256, 0, stream>>>(
        Wp(j), WT[j], COUT[j], CIN[j], PF[j], total);
  }

  // ---- chunked layer chain ----
  for (int cm0 = 0; cm0 < M; cm0 += Pc){
    const int Mc = (M - cm0 < Pc) ? (M - cm0) : Pc;
    const int gx = Mc / 128;

    // forward j=0..10; state alternates bufA/bufB
    u16* src = x0 + (long long)cm0 * 288;
    long long psSrc = psX0;
    int kp = 288;
    u16* dstTbl[2] = { bufA, bufB };
    for (int j = 0; j < 11; ++j){
      u16* dst = dstTbl[j & 1];
      dim3 g(gx, NYF[j]);
      if (j == 10)
        fwd_layer<true><<<g, 512, 0, stream>>>(
            src, psSrc, kp, dst, (long long)Pc * PF[j], gates[j], PF[j],
            WH[j], WL[j], Bp(j), Wp(11), COUT[j]);
      else
        fwd_layer<false><<<g, 512, 0, stream>>>(
            src, psSrc, kp, dst, (long long)Pc * PF[j], gates[j], PF[j],
            WH[j], WL[j], Bp(j), nullptr, COUT[j]);
      src = dst; psSrc = (long long)Pc * PF[j]; kp = PF[j];
    }

    // z output from x_11
    final_z<<<Mc/4, 256, 0, stream>>>(
        src, psSrc, kp, Wp(11), Bp(11), out1, CIN[11], cm0);

    // backward j=10..1; v_10 seed lives in gates[10]
    u16* vin = gates[10];
    for (int j = 10; j >= 1; --j){
      u16* vout = (j & 1) ? vB : vA;
      dim3 g(gx, NYB[j]);
      bwd_layer<<<g, 512, 0, stream>>>(
          vin, PF[j], vout, PF[j-1], gates[j-1], WT[j]);
      vin = vout;
    }

    // g output from v_0
    final_g<<<Mc/4, 256, 0, stream>>>(
        vin, PF[0], Wp(0), CIN[0], out2, COUT[0], cm0);
  }
}